// Round 2
// baseline (584.077 us; speedup 1.0000x reference)
//
#include <hip/hip_runtime.h>

#define NLEVELS 16
#define BLOCK 256
#define PPT 2  // points per thread in pass 1

struct HashParams {
    unsigned offs[NLEVELS + 1];  // per-level table offsets (entries)
    unsigned hsize[NLEVELS];     // per-level table size (entries)
    unsigned hash_bits;          // bit l set -> hash path for level l
    unsigned pow2_bits;          // bit l set -> hsize[l] is a power of two
};

// ---------------- pass 1: level-phased gather+interp -> level-major ws ------
// blockIdx = level * bpl + chunk. Level-major dispatch: each XCD's L2 holds
// ~one 4 MiB level table at a time. ws is level-major ([l][p]) so pass-1
// stores stay confined to one 8 MB slab per level (R1's chunk-local layout
// sprayed all levels' addresses -> +33% FETCH from L2-set pollution).
// xyz is staged once per block into LDS: the 3 stride-12B scalar loads per
// point-level were ~25% of the per-wave distinct-line-touch budget.
__global__ void __launch_bounds__(BLOCK)
hashenc_pass1(const float* __restrict__ xyz,
              const float* __restrict__ emb,
              float2* __restrict__ ws,
              HashParams p, int np, int bpl_shift)
{
    const int l = blockIdx.x >> bpl_shift;
    const int chunk = blockIdx.x & ((1 << bpl_shift) - 1);
    const int tid = threadIdx.x;

    __shared__ float sxyz[BLOCK * PPT * 3];  // 6 KB
    {
        const float4* __restrict__ src =
            (const float4*)(xyz + (size_t)chunk * (BLOCK * PPT) * 3);
        float4* __restrict__ dst = (float4*)sxyz;
#pragma unroll
        for (int i = tid; i < (BLOCK * PPT * 3) / 4; i += BLOCK)
            dst[i] = src[i];
    }
    __syncthreads();

    const unsigned hs = p.hsize[l];
    const float2* __restrict__ tab = (const float2*)emb + p.offs[l];
    const float scale = (float)((16u << l) - 1u);
    const bool do_hash = (p.hash_bits >> l) & 1u;
    const bool is_pow2 = (p.pow2_bits >> l) & 1u;
    float2* __restrict__ wl = ws + (size_t)l * np;

#pragma unroll
    for (int s = 0; s < PPT; ++s) {
        const int lp = s * BLOCK + tid;                     // local point
        const int pidx = chunk * (BLOCK * PPT) + lp;        // global point
        const float x = sxyz[lp * 3 + 0];
        const float y = sxyz[lp * 3 + 1];
        const float z = sxyz[lp * 3 + 2];

        const float px = x * scale + 0.5f;
        const float py = y * scale + 0.5f;
        const float pz = z * scale + 0.5f;
        const float gx = floorf(px), gy = floorf(py), gz = floorf(pz);
        const float fx = px - gx, fy = py - gy, fz = pz - gz;
        const unsigned ix = (unsigned)gx, iy = (unsigned)gy, iz = (unsigned)gz;

        const float wxv[2] = {1.0f - fx, fx};
        const float wyv[2] = {1.0f - fy, fy};
        const float wzv[2] = {1.0f - fz, fz};
        float o0 = 0.0f, o1 = 0.0f;

        if (do_hash && is_pow2) {
            // x-prime is 1: for even ix the two x-corners are v and v^1, an
            // aligned 16 B pair -> one dwordx4 gather replaces two dwordx2.
            const unsigned m = hs - 1u;
            const unsigned hy0 = iy * 2654435761u;
            const unsigned hz0 = iz * 805459861u;
            const unsigned hy1 = hy0 + 2654435761u;
            const unsigned hz1 = hz0 + 805459861u;
            const unsigned hyz[4] = { hy0 ^ hz0, hy1 ^ hz0, hy0 ^ hz1, hy1 ^ hz1 };

            if (!(ix & 1u)) {
                float4 pr[4];
                unsigned vv[4];
#pragma unroll
                for (int q = 0; q < 4; ++q) {
                    vv[q] = (ix ^ hyz[q]) & m;
                    pr[q] = *reinterpret_cast<const float4*>(tab + (vv[q] & ~1u));
                }
#pragma unroll
                for (int q = 0; q < 4; ++q) {
                    const bool sw = (vv[q] & 1u) != 0u;   // entry v in hi half?
                    const float ex0x = sw ? pr[q].z : pr[q].x;
                    const float ex0y = sw ? pr[q].w : pr[q].y;
                    const float ex1x = sw ? pr[q].x : pr[q].z;
                    const float ex1y = sw ? pr[q].y : pr[q].w;
                    // identical association/order to baseline: c ascending
                    const float w0 = wxv[0] * wyv[q & 1] * wzv[(q >> 1) & 1];
                    const float w1 = wxv[1] * wyv[q & 1] * wzv[(q >> 1) & 1];
                    o0 = fmaf(w0, ex0x, o0); o1 = fmaf(w0, ex0y, o1);
                    o0 = fmaf(w1, ex1x, o0); o1 = fmaf(w1, ex1y, o1);
                }
            } else {
                float2 e0[4], e1[4];
#pragma unroll
                for (int q = 0; q < 4; ++q) {
                    e0[q] = tab[(ix ^ hyz[q]) & m];
                    e1[q] = tab[((ix + 1u) ^ hyz[q]) & m];
                }
#pragma unroll
                for (int q = 0; q < 4; ++q) {
                    const float w0 = wxv[0] * wyv[q & 1] * wzv[(q >> 1) & 1];
                    const float w1 = wxv[1] * wyv[q & 1] * wzv[(q >> 1) & 1];
                    o0 = fmaf(w0, e0[q].x, o0); o1 = fmaf(w0, e0[q].y, o1);
                    o0 = fmaf(w1, e1[q].x, o0); o1 = fmaf(w1, e1[q].y, o1);
                }
            }
        } else {
            // non-pow2 hashed levels (0-2) and the (unused) dense path
            unsigned idx[8];
            if (do_hash) {
                const unsigned hy0 = iy * 2654435761u;
                const unsigned hz0 = iz * 805459861u;
                const unsigned hy1 = hy0 + 2654435761u;
                const unsigned hz1 = hz0 + 805459861u;
#pragma unroll
                for (int c = 0; c < 8; ++c)
                    idx[c] = ((ix + (c & 1)) ^ ((c & 2) ? hy1 : hy0) ^ ((c & 4) ? hz1 : hz0)) % hs;
            } else {
                const unsigned stride = (16u << l) + 1u;
#pragma unroll
                for (int c = 0; c < 8; ++c) {
                    const unsigned lin = (ix + (c & 1))
                                       + (iy + ((c >> 1) & 1)) * stride
                                       + (iz + ((c >> 2) & 1)) * stride * stride;
                    idx[c] = lin % hs;
                }
            }
            float2 e[8];
#pragma unroll
            for (int c = 0; c < 8; ++c) e[c] = tab[idx[c]];
#pragma unroll
            for (int c = 0; c < 8; ++c) {
                const float w = wxv[c & 1] * wyv[(c >> 1) & 1] * wzv[(c >> 2) & 1];
                o0 = fmaf(w, e[c].x, o0);
                o1 = fmaf(w, e[c].y, o1);
            }
        }

        wl[pidx] = make_float2(o0, o1);  // coalesced full-line 8B stores
    }
}

// ---------------- pass 2: lean transpose, one thread per out float4 --------
// out[p][32]: float4 j of point p = (ws[2j][p], ws[2j+1][p]). Per wave-load:
// 8 level-streams x 64B contiguous chunks; store is 1 KB fully coalesced.
// No LDS, no syncs — if the ~170 us residual doesn't move, it's overhead,
// not pass-2 structure.
__global__ void __launch_bounds__(BLOCK)
hashenc_pass2(const float2* __restrict__ ws, float4* __restrict__ out4, int np)
{
    const int f = blockIdx.x * BLOCK + threadIdx.x;
    const int p = f >> 3;
    const int j = f & 7;
    const float2 a = ws[(size_t)(2 * j) * np + p];
    const float2 b = ws[(size_t)(2 * j + 1) * np + p];
    out4[f] = make_float4(a.x, a.y, b.x, b.y);
}

// ---------------- fallback: single-pass kernel (used if ws too small) ------
__global__ void __launch_bounds__(BLOCK)
hashenc_fwd(const float* __restrict__ xyz,
            const float* __restrict__ emb,
            float* __restrict__ out,
            HashParams p)
{
    const int tid = threadIdx.x;
    const long b = (long)blockIdx.x * BLOCK + tid;
    __shared__ float lds[BLOCK * 33];

    const float x = xyz[b * 3 + 0];
    const float y = xyz[b * 3 + 1];
    const float z = xyz[b * 3 + 2];

#pragma unroll
    for (int l = 0; l < NLEVELS; ++l) {
        const float scale = (float)((16u << l) - 1u);
        const float px = x * scale + 0.5f;
        const float py = y * scale + 0.5f;
        const float pz = z * scale + 0.5f;
        const float gx = floorf(px), gy = floorf(py), gz = floorf(pz);
        const float fx = px - gx, fy = py - gy, fz = pz - gz;
        const unsigned ix = (unsigned)gx, iy = (unsigned)gy, iz = (unsigned)gz;
        const unsigned hs = p.hsize[l];
        const float2* __restrict__ tab = (const float2*)emb + p.offs[l];

        unsigned idx[8];
        if ((p.hash_bits >> l) & 1u) {
            const unsigned hy0 = iy * 2654435761u;
            const unsigned hz0 = iz * 805459861u;
            const unsigned hy1 = hy0 + 2654435761u;
            const unsigned hz1 = hz0 + 805459861u;
            if ((p.pow2_bits >> l) & 1u) {
                const unsigned m = hs - 1u;
#pragma unroll
                for (int c = 0; c < 8; ++c)
                    idx[c] = ((ix + (c & 1)) ^ ((c & 2) ? hy1 : hy0) ^ ((c & 4) ? hz1 : hz0)) & m;
            } else {
#pragma unroll
                for (int c = 0; c < 8; ++c)
                    idx[c] = ((ix + (c & 1)) ^ ((c & 2) ? hy1 : hy0) ^ ((c & 4) ? hz1 : hz0)) % hs;
            }
        } else {
            const unsigned stride = (16u << l) + 1u;
#pragma unroll
            for (int c = 0; c < 8; ++c) {
                const unsigned lin = (ix + (c & 1))
                                   + (iy + ((c >> 1) & 1)) * stride
                                   + (iz + ((c >> 2) & 1)) * stride * stride;
                idx[c] = lin % hs;
            }
        }

        float2 e[8];
#pragma unroll
        for (int c = 0; c < 8; ++c) e[c] = tab[idx[c]];

        const float wx[2] = {1.0f - fx, fx};
        const float wy[2] = {1.0f - fy, fy};
        const float wz[2] = {1.0f - fz, fz};
        float o0 = 0.0f, o1 = 0.0f;
#pragma unroll
        for (int c = 0; c < 8; ++c) {
            const float w = wx[c & 1] * wy[(c >> 1) & 1] * wz[(c >> 2) & 1];
            o0 = fmaf(w, e[c].x, o0);
            o1 = fmaf(w, e[c].y, o1);
        }
        lds[tid * 33 + l * 2 + 0] = o0;
        lds[tid * 33 + l * 2 + 1] = o1;
    }

    __syncthreads();
    float* __restrict__ ochunk = out + (long)blockIdx.x * (BLOCK * 32);
#pragma unroll
    for (int k = 0; k < 32; ++k) {
        const int flat = k * BLOCK + tid;
        const float v = lds[(flat >> 5) * 33 + (flat & 31)];
        __builtin_nontemporal_store(v, ochunk + flat);
    }
}

extern "C" void kernel_launch(void* const* d_in, const int* in_sizes, int n_in,
                              void* d_out, int out_size, void* d_ws, size_t ws_size,
                              hipStream_t stream) {
    const float* xyz = (const float*)d_in[0];
    const float* emb = (const float*)d_in[1];
    float* out = (float*)d_out;
    const int B = in_sizes[0] / 3;

    // Reproduce HashEncoder.__init__ offset arithmetic exactly.
    HashParams p;
    p.offs[0] = 0;
    unsigned hash_bits = 0, pow2_bits = 0;
    long off = 0;
    for (int i = 0; i < NLEVELS; ++i) {
        const long res = 16L << i;
        const long dense = (res + 1) * (res + 1) * (res + 1);
        long t = dense < (1L << 19) ? dense : (1L << 19);
        t = (t / 8) * 8;
        p.hsize[i] = (unsigned)t;
        off += t;
        p.offs[i + 1] = (unsigned)off;
        if (dense > t) hash_bits |= (1u << i);
        if ((t & (t - 1)) == 0) pow2_bits |= (1u << i);
    }
    p.hash_bits = hash_bits;
    p.pow2_bits = pow2_bits;

    const size_t need = (size_t)B * NLEVELS * sizeof(float2);
    const long nf4 = (long)B * 8;  // out float4 count
    if (ws_size >= need && (B % (BLOCK * PPT)) == 0 && (nf4 % BLOCK) == 0) {
        int bpl_shift = 0;
        while ((1 << bpl_shift) * (BLOCK * PPT) < B) ++bpl_shift;  // B is pow2
        const int bpl = 1 << bpl_shift;
        hashenc_pass1<<<dim3(NLEVELS * bpl), dim3(BLOCK), 0, stream>>>(
            xyz, emb, (float2*)d_ws, p, B, bpl_shift);
        hashenc_pass2<<<dim3((int)(nf4 / BLOCK)), dim3(BLOCK), 0, stream>>>(
            (const float2*)d_ws, (float4*)out, B);
    } else {
        hashenc_fwd<<<dim3(B / BLOCK), dim3(BLOCK), 0, stream>>>(xyz, emb, out, p);
    }
}

// Round 3
// 583.302 us; speedup vs baseline: 1.0013x; 1.0013x over previous
//
#include <hip/hip_runtime.h>
#include <hip/hip_fp16.h>

#define NLEVELS 16
#define BLOCK 256
#define PPT 2  // points per thread in pass 1

struct HashParams {
    unsigned offs[NLEVELS + 1];  // per-level table offsets (entries)
    unsigned hsize[NLEVELS];     // per-level table size (entries)
    unsigned hash_bits;          // bit l set -> hash path for level l
    unsigned pow2_bits;          // bit l set -> hsize[l] is a power of two
};

// ---------------- table conversion: f32x2 entry -> packed half2 (4 B) ------
// Entries are uniform(-1e-4,1e-4); fp16 subnormal step is 2^-24 ~= 6e-8, so
// per-entry rounding error <= 3e-8 -> interp error ~5e-8, negligible vs the
// existing 4.8e-7 absmax. Halves gather bytes AND halves each level table to
// 2 MB -> L2-resident per XCD during its level phase.
__global__ void __launch_bounds__(BLOCK)
hashenc_conv(const float4* __restrict__ emb2, uint2* __restrict__ tab16, int n2)
{
    const int i = blockIdx.x * BLOCK + threadIdx.x;
    if (i < n2) {
        const float4 v = emb2[i];
        const __half2 a = __floats2half2_rn(v.x, v.y);
        const __half2 b = __floats2half2_rn(v.z, v.w);
        tab16[i] = make_uint2(*(const unsigned*)&a, *(const unsigned*)&b);
    }
}

// ---------------- pass 1 (fp16 table): issue-all-then-consume ---------------
// Phase A computes indices and issues ALL gathers for both PPT points into
// registers (2x memory-level parallelism vs per-point interleave), phase B
// converts+interpolates. Level-major ws + level-major dispatch keep each
// XCD's L2 on one table. Requires: every hashed level pow2 (checked on host).
__global__ void __launch_bounds__(BLOCK)
hashenc_pass1_h(const float* __restrict__ xyz,
                const unsigned* __restrict__ tab16,
                float2* __restrict__ ws,
                HashParams p, int np, int bpl_shift)
{
    const int l = blockIdx.x >> bpl_shift;
    const int chunk = blockIdx.x & ((1 << bpl_shift) - 1);
    const int tid = threadIdx.x;

    __shared__ float sxyz[BLOCK * PPT * 3];  // 6 KB staged coords
    {
        const float4* __restrict__ src =
            (const float4*)(xyz + (size_t)chunk * (BLOCK * PPT) * 3);
        float4* __restrict__ dst = (float4*)sxyz;
#pragma unroll
        for (int i = tid; i < (BLOCK * PPT * 3) / 4; i += BLOCK)
            dst[i] = src[i];
    }
    __syncthreads();

    const unsigned hs = p.hsize[l];
    const unsigned* __restrict__ tab = tab16 + p.offs[l];
    const float scale = (float)((16u << l) - 1u);
    const bool do_hash = (p.hash_bits >> l) & 1u;
    float2* __restrict__ wl = ws + (size_t)l * np;

    unsigned raw[PPT][8];    // all compile-time indexed (rule #20)
    unsigned selba[PPT];     // bit q: swap r0/r1 for corner-pair q
    float fxa[PPT], fya[PPT], fza[PPT];

    // ---- phase A: indices + issue gathers ----
#pragma unroll
    for (int s = 0; s < PPT; ++s) {
        const int lp = s * BLOCK + tid;
        const float x = sxyz[lp * 3 + 0];
        const float y = sxyz[lp * 3 + 1];
        const float z = sxyz[lp * 3 + 2];
        const float px = x * scale + 0.5f;
        const float py = y * scale + 0.5f;
        const float pz = z * scale + 0.5f;
        const float gx = floorf(px), gy = floorf(py), gz = floorf(pz);
        fxa[s] = px - gx; fya[s] = py - gy; fza[s] = pz - gz;
        const unsigned ix = (unsigned)gx, iy = (unsigned)gy, iz = (unsigned)gz;

        unsigned selb = 0u;
        if (do_hash) {  // hashed => pow2 (host-verified)
            const unsigned m = hs - 1u;
            const unsigned hy0 = iy * 2654435761u;
            const unsigned hz0 = iz * 805459861u;
            const unsigned hy1 = hy0 + 2654435761u;
            const unsigned hz1 = hz0 + 805459861u;
            const unsigned hyz[4] = { hy0 ^ hz0, hy1 ^ hz0, hy0 ^ hz1, hy1 ^ hz1 };
            if (!(ix & 1u)) {
                // even ix: x-corners are v0 and v0^1 -> one 8 B dwordx2 pair
#pragma unroll
                for (int q = 0; q < 4; ++q) {
                    const unsigned v0 = (ix ^ hyz[q]) & m;
                    const uint2 pr = *reinterpret_cast<const uint2*>(tab + (v0 & ~1u));
                    raw[s][2 * q]     = pr.x;   // entry v0&~1
                    raw[s][2 * q + 1] = pr.y;   // entry v0|1
                    selb |= (v0 & 1u) << q;     // v0 odd -> corner0 is pr.y
                }
            } else {
#pragma unroll
                for (int q = 0; q < 4; ++q) {
                    raw[s][2 * q]     = tab[(ix ^ hyz[q]) & m];
                    raw[s][2 * q + 1] = tab[((ix + 1u) ^ hyz[q]) & m];
                }
            }
        } else {
            // dense: lin < 2*hs always (hs = dense rounded down to mult of 8),
            // so % becomes compare-subtract.
            const unsigned stride = (16u << l) + 1u;
#pragma unroll
            for (int q = 0; q < 4; ++q) {
                const unsigned base = ix + (iy + (q & 1u)) * stride
                                         + (iz + (unsigned)(q >> 1)) * stride * stride;
                const unsigned l0 = base, l1 = base + 1u;
                const unsigned v0 = l0 - (l0 >= hs ? hs : 0u);
                const unsigned v1 = l1 - (l1 >= hs ? hs : 0u);
                raw[s][2 * q]     = tab[v0];
                raw[s][2 * q + 1] = tab[v1];
            }
        }
        selba[s] = selb;
    }

    // ---- phase B: convert + trilinear interp + store ----
#pragma unroll
    for (int s = 0; s < PPT; ++s) {
        const float fx = fxa[s], fy = fya[s], fz = fza[s];
        const float wxv[2] = {1.0f - fx, fx};
        const float wyv[2] = {1.0f - fy, fy};
        const float wzv[2] = {1.0f - fz, fz};
        const unsigned selb = selba[s];
        float o0 = 0.0f, o1 = 0.0f;
#pragma unroll
        for (int q = 0; q < 4; ++q) {
            const unsigned r0 = raw[s][2 * q], r1 = raw[s][2 * q + 1];
            const bool sw = (selb >> q) & 1u;
            const unsigned ua = sw ? r1 : r0;   // corner cx=0
            const unsigned ub = sw ? r0 : r1;   // corner cx=1
            const float2 ea = __half22float2(*reinterpret_cast<const __half2*>(&ua));
            const float2 eb = __half22float2(*reinterpret_cast<const __half2*>(&ub));
            const float wq = wyv[q & 1] * wzv[q >> 1];
            const float w0 = wxv[0] * wq, w1 = wxv[1] * wq;
            o0 = fmaf(w0, ea.x, o0); o1 = fmaf(w0, ea.y, o1);
            o0 = fmaf(w1, eb.x, o0); o1 = fmaf(w1, eb.y, o1);
        }
        const int pidx = chunk * (BLOCK * PPT) + s * BLOCK + tid;
        wl[pidx] = make_float2(o0, o1);
    }
}

// ---------------- pass 1 fallback (f32 table, R2 version) -------------------
__global__ void __launch_bounds__(BLOCK)
hashenc_pass1_f32(const float* __restrict__ xyz,
                  const float* __restrict__ emb,
                  float2* __restrict__ ws,
                  HashParams p, int np, int bpl_shift)
{
    const int l = blockIdx.x >> bpl_shift;
    const int chunk = blockIdx.x & ((1 << bpl_shift) - 1);
    const int tid = threadIdx.x;

    __shared__ float sxyz[BLOCK * PPT * 3];
    {
        const float4* __restrict__ src =
            (const float4*)(xyz + (size_t)chunk * (BLOCK * PPT) * 3);
        float4* __restrict__ dst = (float4*)sxyz;
#pragma unroll
        for (int i = tid; i < (BLOCK * PPT * 3) / 4; i += BLOCK)
            dst[i] = src[i];
    }
    __syncthreads();

    const unsigned hs = p.hsize[l];
    const float2* __restrict__ tab = (const float2*)emb + p.offs[l];
    const float scale = (float)((16u << l) - 1u);
    const bool do_hash = (p.hash_bits >> l) & 1u;
    const bool is_pow2 = (p.pow2_bits >> l) & 1u;
    float2* __restrict__ wl = ws + (size_t)l * np;

#pragma unroll
    for (int s = 0; s < PPT; ++s) {
        const int lp = s * BLOCK + tid;
        const int pidx = chunk * (BLOCK * PPT) + lp;
        const float x = sxyz[lp * 3 + 0];
        const float y = sxyz[lp * 3 + 1];
        const float z = sxyz[lp * 3 + 2];
        const float px = x * scale + 0.5f;
        const float py = y * scale + 0.5f;
        const float pz = z * scale + 0.5f;
        const float gx = floorf(px), gy = floorf(py), gz = floorf(pz);
        const float fx = px - gx, fy = py - gy, fz = pz - gz;
        const unsigned ix = (unsigned)gx, iy = (unsigned)gy, iz = (unsigned)gz;
        const float wxv[2] = {1.0f - fx, fx};
        const float wyv[2] = {1.0f - fy, fy};
        const float wzv[2] = {1.0f - fz, fz};
        float o0 = 0.0f, o1 = 0.0f;
        unsigned idx[8];
        if (do_hash) {
            const unsigned hy0 = iy * 2654435761u;
            const unsigned hz0 = iz * 805459861u;
            const unsigned hy1 = hy0 + 2654435761u;
            const unsigned hz1 = hz0 + 805459861u;
            if (is_pow2) {
                const unsigned m = hs - 1u;
#pragma unroll
                for (int c = 0; c < 8; ++c)
                    idx[c] = ((ix + (c & 1)) ^ ((c & 2) ? hy1 : hy0) ^ ((c & 4) ? hz1 : hz0)) & m;
            } else {
#pragma unroll
                for (int c = 0; c < 8; ++c)
                    idx[c] = ((ix + (c & 1)) ^ ((c & 2) ? hy1 : hy0) ^ ((c & 4) ? hz1 : hz0)) % hs;
            }
        } else {
            const unsigned stride = (16u << l) + 1u;
#pragma unroll
            for (int c = 0; c < 8; ++c) {
                const unsigned lin = (ix + (c & 1))
                                   + (iy + ((c >> 1) & 1)) * stride
                                   + (iz + ((c >> 2) & 1)) * stride * stride;
                idx[c] = lin % hs;
            }
        }
        float2 e[8];
#pragma unroll
        for (int c = 0; c < 8; ++c) e[c] = tab[idx[c]];
#pragma unroll
        for (int c = 0; c < 8; ++c) {
            const float w = wxv[c & 1] * wyv[(c >> 1) & 1] * wzv[(c >> 2) & 1];
            o0 = fmaf(w, e[c].x, o0);
            o1 = fmaf(w, e[c].y, o1);
        }
        wl[pidx] = make_float2(o0, o1);
    }
}

// ---------------- pass 2: LDS transpose (level-major ws) --------------------
__global__ void __launch_bounds__(BLOCK)
hashenc_pass2(const float2* __restrict__ ws, float* __restrict__ out, int np)
{
    __shared__ float lds[BLOCK * 33];
    const int tid = threadIdx.x;
    const int p0 = blockIdx.x * BLOCK;

#pragma unroll
    for (int l = 0; l < NLEVELS; ++l) {
        const float2 v = ws[(size_t)l * np + p0 + tid];  // coalesced per level
        lds[tid * 33 + 2 * l + 0] = v.x;                 // bank (tid+2l)%32: conflict-free
        lds[tid * 33 + 2 * l + 1] = v.y;
    }
    __syncthreads();
    float* __restrict__ ochunk = out + (size_t)blockIdx.x * (BLOCK * 32);
#pragma unroll
    for (int k = 0; k < 32; ++k) {
        const int flat = k * BLOCK + tid;
        const float v = lds[(flat >> 5) * 33 + (flat & 31)];
        __builtin_nontemporal_store(v, ochunk + flat);
    }
}

// ---------------- fallback: single-pass kernel (ws too small) ---------------
__global__ void __launch_bounds__(BLOCK)
hashenc_fwd(const float* __restrict__ xyz,
            const float* __restrict__ emb,
            float* __restrict__ out,
            HashParams p)
{
    const int tid = threadIdx.x;
    const long b = (long)blockIdx.x * BLOCK + tid;
    __shared__ float lds[BLOCK * 33];

    const float x = xyz[b * 3 + 0];
    const float y = xyz[b * 3 + 1];
    const float z = xyz[b * 3 + 2];

#pragma unroll
    for (int l = 0; l < NLEVELS; ++l) {
        const float scale = (float)((16u << l) - 1u);
        const float px = x * scale + 0.5f;
        const float py = y * scale + 0.5f;
        const float pz = z * scale + 0.5f;
        const float gx = floorf(px), gy = floorf(py), gz = floorf(pz);
        const float fx = px - gx, fy = py - gy, fz = pz - gz;
        const unsigned ix = (unsigned)gx, iy = (unsigned)gy, iz = (unsigned)gz;
        const unsigned hs = p.hsize[l];
        const float2* __restrict__ tab = (const float2*)emb + p.offs[l];

        unsigned idx[8];
        if ((p.hash_bits >> l) & 1u) {
            const unsigned hy0 = iy * 2654435761u;
            const unsigned hz0 = iz * 805459861u;
            const unsigned hy1 = hy0 + 2654435761u;
            const unsigned hz1 = hz0 + 805459861u;
            if ((p.pow2_bits >> l) & 1u) {
                const unsigned m = hs - 1u;
#pragma unroll
                for (int c = 0; c < 8; ++c)
                    idx[c] = ((ix + (c & 1)) ^ ((c & 2) ? hy1 : hy0) ^ ((c & 4) ? hz1 : hz0)) & m;
            } else {
#pragma unroll
                for (int c = 0; c < 8; ++c)
                    idx[c] = ((ix + (c & 1)) ^ ((c & 2) ? hy1 : hy0) ^ ((c & 4) ? hz1 : hz0)) % hs;
            }
        } else {
            const unsigned stride = (16u << l) + 1u;
#pragma unroll
            for (int c = 0; c < 8; ++c) {
                const unsigned lin = (ix + (c & 1))
                                   + (iy + ((c >> 1) & 1)) * stride
                                   + (iz + ((c >> 2) & 1)) * stride * stride;
                idx[c] = lin % hs;
            }
        }

        float2 e[8];
#pragma unroll
        for (int c = 0; c < 8; ++c) e[c] = tab[idx[c]];

        const float wx[2] = {1.0f - fx, fx};
        const float wy[2] = {1.0f - fy, fy};
        const float wz[2] = {1.0f - fz, fz};
        float o0 = 0.0f, o1 = 0.0f;
#pragma unroll
        for (int c = 0; c < 8; ++c) {
            const float w = wx[c & 1] * wy[(c >> 1) & 1] * wz[(c >> 2) & 1];
            o0 = fmaf(w, e[c].x, o0);
            o1 = fmaf(w, e[c].y, o1);
        }
        lds[tid * 33 + l * 2 + 0] = o0;
        lds[tid * 33 + l * 2 + 1] = o1;
    }

    __syncthreads();
    float* __restrict__ ochunk = out + (long)blockIdx.x * (BLOCK * 32);
#pragma unroll
    for (int k = 0; k < 32; ++k) {
        const int flat = k * BLOCK + tid;
        const float v = lds[(flat >> 5) * 33 + (flat & 31)];
        __builtin_nontemporal_store(v, ochunk + flat);
    }
}

extern "C" void kernel_launch(void* const* d_in, const int* in_sizes, int n_in,
                              void* d_out, int out_size, void* d_ws, size_t ws_size,
                              hipStream_t stream) {
    const float* xyz = (const float*)d_in[0];
    const float* emb = (const float*)d_in[1];
    float* out = (float*)d_out;
    const int B = in_sizes[0] / 3;

    // Reproduce HashEncoder.__init__ offset arithmetic exactly.
    HashParams p;
    p.offs[0] = 0;
    unsigned hash_bits = 0, pow2_bits = 0;
    long off = 0;
    for (int i = 0; i < NLEVELS; ++i) {
        const long res = 16L << i;
        const long dense = (res + 1) * (res + 1) * (res + 1);
        long t = dense < (1L << 19) ? dense : (1L << 19);
        t = (t / 8) * 8;
        p.hsize[i] = (unsigned)t;
        off += t;
        p.offs[i + 1] = (unsigned)off;
        if (dense > t) hash_bits |= (1u << i);
        if ((t & (t - 1)) == 0) pow2_bits |= (1u << i);
    }
    p.hash_bits = hash_bits;
    p.pow2_bits = pow2_bits;

    const long nent = off;                              // total table entries
    const size_t need = (size_t)B * NLEVELS * sizeof(float2);
    const size_t need_h = need + (size_t)nent * 4;      // + fp16 table copy
    const bool shape_ok = (B % (BLOCK * PPT)) == 0 && (B % BLOCK) == 0;
    const bool hashed_all_pow2 = (hash_bits & ~pow2_bits) == 0;

    if (shape_ok && hashed_all_pow2 && ws_size >= need_h) {
        // tier 1: fp16 table
        unsigned* tab16 = (unsigned*)((char*)d_ws + need);
        const int n2 = (int)(nent / 2);
        hashenc_conv<<<dim3((n2 + BLOCK - 1) / BLOCK), dim3(BLOCK), 0, stream>>>(
            (const float4*)emb, (uint2*)tab16, n2);
        int bpl_shift = 0;
        while ((1 << bpl_shift) * (BLOCK * PPT) < B) ++bpl_shift;  // B is pow2
        const int bpl = 1 << bpl_shift;
        hashenc_pass1_h<<<dim3(NLEVELS * bpl), dim3(BLOCK), 0, stream>>>(
            xyz, tab16, (float2*)d_ws, p, B, bpl_shift);
        hashenc_pass2<<<dim3(B / BLOCK), dim3(BLOCK), 0, stream>>>(
            (const float2*)d_ws, out, B);
    } else if (shape_ok && ws_size >= need) {
        // tier 2: f32 table two-pass
        int bpl_shift = 0;
        while ((1 << bpl_shift) * (BLOCK * PPT) < B) ++bpl_shift;
        const int bpl = 1 << bpl_shift;
        hashenc_pass1_f32<<<dim3(NLEVELS * bpl), dim3(BLOCK), 0, stream>>>(
            xyz, emb, (float2*)d_ws, p, B, bpl_shift);
        hashenc_pass2<<<dim3(B / BLOCK), dim3(BLOCK), 0, stream>>>(
            (const float2*)d_ws, out, B);
    } else {
        // tier 3: single-pass fallback
        hashenc_fwd<<<dim3(B / BLOCK), dim3(BLOCK), 0, stream>>>(xyz, emb, out, p);
    }
}

// Round 4
// 487.314 us; speedup vs baseline: 1.1986x; 1.1970x over previous
//
#include <hip/hip_runtime.h>
#include <hip/hip_fp16.h>

#define NLEVELS 16
#define BLOCK 256
#define PPT 2  // points per thread in pass 1

struct HashParams {
    unsigned offs[NLEVELS + 1];  // per-level table offsets (entries)
    unsigned hsize[NLEVELS];     // per-level table size (entries)
    unsigned hash_bits;          // bit l set -> hash path for level l (always, this config)
    unsigned pow2_bits;          // bit l set -> hsize[l] is a power of two
};

// ---------------- table conversion: f32x2 entry -> packed half2 (4 B) ------
// Entries are uniform(-1e-4,1e-4); fp16 step there is 2^-24 ~= 6e-8, so
// rounding error <= 3e-8/entry. Halves gather bytes AND halves each hashed
// level table to 2 MB -> L2-resident per XCD during its level phase (the 4 MB
// f32 tables exactly thrashed the 4 MB XCD L2 -> ~650 MB HBM refill traffic).
__global__ void __launch_bounds__(BLOCK)
hashenc_conv(const float4* __restrict__ emb2, uint2* __restrict__ tab16, int n2)
{
    const int i = blockIdx.x * BLOCK + threadIdx.x;
    if (i < n2) {
        const float4 v = emb2[i];
        const __half2 a = __floats2half2_rn(v.x, v.y);
        const __half2 b = __floats2half2_rn(v.z, v.w);
        tab16[i] = make_uint2(*(const unsigned*)&a, *(const unsigned*)&b);
    }
}

// ---------------- pass 1 (fp16 table): issue-all-then-consume ---------------
// Level-major dispatch (blockIdx = level*bpl + chunk): each XCD's L2 holds one
// 2 MB fp16 table at a time. Phase A computes indices and issues ALL gathers
// for both PPT points into registers, phase B converts+interpolates.
// ws is level-major packed half2 (4 B/point-level): 64 MB total -> L3-resident.
__global__ void __launch_bounds__(BLOCK)
hashenc_pass1_h(const float* __restrict__ xyz,
                const unsigned* __restrict__ tab16,
                unsigned* __restrict__ ws,
                HashParams p, int np, int bpl_shift)
{
    const int l = blockIdx.x >> bpl_shift;
    const int chunk = blockIdx.x & ((1 << bpl_shift) - 1);
    const int tid = threadIdx.x;

    __shared__ float sxyz[BLOCK * PPT * 3];  // 6 KB staged coords
    {
        const float4* __restrict__ src =
            (const float4*)(xyz + (size_t)chunk * (BLOCK * PPT) * 3);
        float4* __restrict__ dst = (float4*)sxyz;
#pragma unroll
        for (int i = tid; i < (BLOCK * PPT * 3) / 4; i += BLOCK)
            dst[i] = src[i];
    }
    __syncthreads();

    const unsigned hs = p.hsize[l];
    const unsigned* __restrict__ tab = tab16 + p.offs[l];
    const float scale = (float)((16u << l) - 1u);
    const bool is_pow2 = (p.pow2_bits >> l) & 1u;
    unsigned* __restrict__ wl = ws + (size_t)l * np;

    unsigned raw[PPT][8];    // all compile-time indexed
    unsigned selba[PPT];     // bit q: swap r0/r1 for corner-pair q
    float fxa[PPT], fya[PPT], fza[PPT];

    // ---- phase A: indices + issue gathers ----
#pragma unroll
    for (int s = 0; s < PPT; ++s) {
        const int lp = s * BLOCK + tid;
        const float x = sxyz[lp * 3 + 0];
        const float y = sxyz[lp * 3 + 1];
        const float z = sxyz[lp * 3 + 2];
        const float px = x * scale + 0.5f;
        const float py = y * scale + 0.5f;
        const float pz = z * scale + 0.5f;
        const float gx = floorf(px), gy = floorf(py), gz = floorf(pz);
        fxa[s] = px - gx; fya[s] = py - gy; fza[s] = pz - gz;
        const unsigned ix = (unsigned)gx, iy = (unsigned)gy, iz = (unsigned)gz;

        const unsigned hy0 = iy * 2654435761u;
        const unsigned hz0 = iz * 805459861u;
        const unsigned hy1 = hy0 + 2654435761u;
        const unsigned hz1 = hz0 + 805459861u;
        const unsigned hyz[4] = { hy0 ^ hz0, hy1 ^ hz0, hy0 ^ hz1, hy1 ^ hz1 };

        unsigned selb = 0u;
        if (is_pow2) {
            const unsigned m = hs - 1u;
            if (!(ix & 1u)) {
                // even ix: x-corners are v0 and v0^1 -> one 8 B dwordx2 pair
#pragma unroll
                for (int q = 0; q < 4; ++q) {
                    const unsigned v0 = (ix ^ hyz[q]) & m;
                    const uint2 pr = *reinterpret_cast<const uint2*>(tab + (v0 & ~1u));
                    raw[s][2 * q]     = pr.x;   // entry v0&~1
                    raw[s][2 * q + 1] = pr.y;   // entry v0|1
                    selb |= (v0 & 1u) << q;     // v0 odd -> corner cx=0 is pr.y
                }
            } else {
#pragma unroll
                for (int q = 0; q < 4; ++q) {
                    raw[s][2 * q]     = tab[(ix ^ hyz[q]) & m];
                    raw[s][2 * q + 1] = tab[((ix + 1u) ^ hyz[q]) & m];
                }
            }
        } else {
            // non-pow2 hashed levels (0-2): tables are tiny & cache-hot; % is fine
#pragma unroll
            for (int q = 0; q < 4; ++q) {
                raw[s][2 * q]     = tab[(ix ^ hyz[q]) % hs];
                raw[s][2 * q + 1] = tab[((ix + 1u) ^ hyz[q]) % hs];
            }
        }
        selba[s] = selb;
    }

    // ---- phase B: convert + trilinear interp + packed store ----
#pragma unroll
    for (int s = 0; s < PPT; ++s) {
        const float fx = fxa[s], fy = fya[s], fz = fza[s];
        const float wxv[2] = {1.0f - fx, fx};
        const float wyv[2] = {1.0f - fy, fy};
        const float wzv[2] = {1.0f - fz, fz};
        const unsigned selb = selba[s];
        float o0 = 0.0f, o1 = 0.0f;
#pragma unroll
        for (int q = 0; q < 4; ++q) {
            const unsigned r0 = raw[s][2 * q], r1 = raw[s][2 * q + 1];
            const bool sw = (selb >> q) & 1u;
            const unsigned ua = sw ? r1 : r0;   // corner cx=0
            const unsigned ub = sw ? r0 : r1;   // corner cx=1
            const float2 ea = __half22float2(*reinterpret_cast<const __half2*>(&ua));
            const float2 eb = __half22float2(*reinterpret_cast<const __half2*>(&ub));
            const float wq = wyv[q & 1] * wzv[q >> 1];
            const float w0 = wxv[0] * wq, w1 = wxv[1] * wq;
            o0 = fmaf(w0, ea.x, o0); o1 = fmaf(w0, ea.y, o1);
            o0 = fmaf(w1, eb.x, o0); o1 = fmaf(w1, eb.y, o1);
        }
        const int pidx = chunk * (BLOCK * PPT) + s * BLOCK + tid;
        const __half2 ph = __floats2half2_rn(o0, o1);
        wl[pidx] = *(const unsigned*)&ph;   // 4 B coalesced store
    }
}

// ---------------- pass 2: LDS transpose, half2 ws -> f32 out ---------------
__global__ void __launch_bounds__(BLOCK)
hashenc_pass2_h(const unsigned* __restrict__ ws, float* __restrict__ out, int np)
{
    __shared__ float lds[BLOCK * 33];
    const int tid = threadIdx.x;
    const int p0 = blockIdx.x * BLOCK;

#pragma unroll
    for (int l = 0; l < NLEVELS; ++l) {
        const unsigned u = ws[(size_t)l * np + p0 + tid];   // coalesced 4 B/lane
        const float2 v = __half22float2(*reinterpret_cast<const __half2*>(&u));
        lds[tid * 33 + 2 * l + 0] = v.x;    // bank (tid+2l)%32: conflict-free
        lds[tid * 33 + 2 * l + 1] = v.y;
    }
    __syncthreads();
    float* __restrict__ ochunk = out + (size_t)blockIdx.x * (BLOCK * 32);
#pragma unroll
    for (int k = 0; k < 32; ++k) {
        const int flat = k * BLOCK + tid;
        const float v = lds[(flat >> 5) * 33 + (flat & 31)];
        __builtin_nontemporal_store(v, ochunk + flat);
    }
}

// ---------------- tier 2: f32 two-pass (R3 version) -------------------------
__global__ void __launch_bounds__(BLOCK)
hashenc_pass1_f32(const float* __restrict__ xyz,
                  const float* __restrict__ emb,
                  float2* __restrict__ ws,
                  HashParams p, int np, int bpl_shift)
{
    const int l = blockIdx.x >> bpl_shift;
    const int chunk = blockIdx.x & ((1 << bpl_shift) - 1);
    const int tid = threadIdx.x;

    __shared__ float sxyz[BLOCK * PPT * 3];
    {
        const float4* __restrict__ src =
            (const float4*)(xyz + (size_t)chunk * (BLOCK * PPT) * 3);
        float4* __restrict__ dst = (float4*)sxyz;
#pragma unroll
        for (int i = tid; i < (BLOCK * PPT * 3) / 4; i += BLOCK)
            dst[i] = src[i];
    }
    __syncthreads();

    const unsigned hs = p.hsize[l];
    const float2* __restrict__ tab = (const float2*)emb + p.offs[l];
    const float scale = (float)((16u << l) - 1u);
    const bool do_hash = (p.hash_bits >> l) & 1u;
    const bool is_pow2 = (p.pow2_bits >> l) & 1u;
    float2* __restrict__ wl = ws + (size_t)l * np;

#pragma unroll
    for (int s = 0; s < PPT; ++s) {
        const int lp = s * BLOCK + tid;
        const int pidx = chunk * (BLOCK * PPT) + lp;
        const float x = sxyz[lp * 3 + 0];
        const float y = sxyz[lp * 3 + 1];
        const float z = sxyz[lp * 3 + 2];
        const float px = x * scale + 0.5f;
        const float py = y * scale + 0.5f;
        const float pz = z * scale + 0.5f;
        const float gx = floorf(px), gy = floorf(py), gz = floorf(pz);
        const float fx = px - gx, fy = py - gy, fz = pz - gz;
        const unsigned ix = (unsigned)gx, iy = (unsigned)gy, iz = (unsigned)gz;
        const float wxv[2] = {1.0f - fx, fx};
        const float wyv[2] = {1.0f - fy, fy};
        const float wzv[2] = {1.0f - fz, fz};
        float o0 = 0.0f, o1 = 0.0f;
        unsigned idx[8];
        if (do_hash) {
            const unsigned hy0 = iy * 2654435761u;
            const unsigned hz0 = iz * 805459861u;
            const unsigned hy1 = hy0 + 2654435761u;
            const unsigned hz1 = hz0 + 805459861u;
            if (is_pow2) {
                const unsigned m = hs - 1u;
#pragma unroll
                for (int c = 0; c < 8; ++c)
                    idx[c] = ((ix + (c & 1)) ^ ((c & 2) ? hy1 : hy0) ^ ((c & 4) ? hz1 : hz0)) & m;
            } else {
#pragma unroll
                for (int c = 0; c < 8; ++c)
                    idx[c] = ((ix + (c & 1)) ^ ((c & 2) ? hy1 : hy0) ^ ((c & 4) ? hz1 : hz0)) % hs;
            }
        } else {
            const unsigned stride = (16u << l) + 1u;
#pragma unroll
            for (int c = 0; c < 8; ++c) {
                const unsigned lin = (ix + (c & 1))
                                   + (iy + ((c >> 1) & 1)) * stride
                                   + (iz + ((c >> 2) & 1)) * stride * stride;
                idx[c] = lin % hs;
            }
        }
        float2 e[8];
#pragma unroll
        for (int c = 0; c < 8; ++c) e[c] = tab[idx[c]];
#pragma unroll
        for (int c = 0; c < 8; ++c) {
            const float w = wxv[c & 1] * wyv[(c >> 1) & 1] * wzv[(c >> 2) & 1];
            o0 = fmaf(w, e[c].x, o0);
            o1 = fmaf(w, e[c].y, o1);
        }
        wl[pidx] = make_float2(o0, o1);
    }
}

__global__ void __launch_bounds__(BLOCK)
hashenc_pass2(const float2* __restrict__ ws, float* __restrict__ out, int np)
{
    __shared__ float lds[BLOCK * 33];
    const int tid = threadIdx.x;
    const int p0 = blockIdx.x * BLOCK;

#pragma unroll
    for (int l = 0; l < NLEVELS; ++l) {
        const float2 v = ws[(size_t)l * np + p0 + tid];
        lds[tid * 33 + 2 * l + 0] = v.x;
        lds[tid * 33 + 2 * l + 1] = v.y;
    }
    __syncthreads();
    float* __restrict__ ochunk = out + (size_t)blockIdx.x * (BLOCK * 32);
#pragma unroll
    for (int k = 0; k < 32; ++k) {
        const int flat = k * BLOCK + tid;
        const float v = lds[(flat >> 5) * 33 + (flat & 31)];
        __builtin_nontemporal_store(v, ochunk + flat);
    }
}

// ---------------- tier 3: single-pass fallback ------------------------------
__global__ void __launch_bounds__(BLOCK)
hashenc_fwd(const float* __restrict__ xyz,
            const float* __restrict__ emb,
            float* __restrict__ out,
            HashParams p)
{
    const int tid = threadIdx.x;
    const long b = (long)blockIdx.x * BLOCK + tid;
    __shared__ float lds[BLOCK * 33];

    const float x = xyz[b * 3 + 0];
    const float y = xyz[b * 3 + 1];
    const float z = xyz[b * 3 + 2];

#pragma unroll
    for (int l = 0; l < NLEVELS; ++l) {
        const float scale = (float)((16u << l) - 1u);
        const float px = x * scale + 0.5f;
        const float py = y * scale + 0.5f;
        const float pz = z * scale + 0.5f;
        const float gx = floorf(px), gy = floorf(py), gz = floorf(pz);
        const float fx = px - gx, fy = py - gy, fz = pz - gz;
        const unsigned ix = (unsigned)gx, iy = (unsigned)gy, iz = (unsigned)gz;
        const unsigned hs = p.hsize[l];
        const float2* __restrict__ tab = (const float2*)emb + p.offs[l];

        unsigned idx[8];
        if ((p.hash_bits >> l) & 1u) {
            const unsigned hy0 = iy * 2654435761u;
            const unsigned hz0 = iz * 805459861u;
            const unsigned hy1 = hy0 + 2654435761u;
            const unsigned hz1 = hz0 + 805459861u;
            if ((p.pow2_bits >> l) & 1u) {
                const unsigned m = hs - 1u;
#pragma unroll
                for (int c = 0; c < 8; ++c)
                    idx[c] = ((ix + (c & 1)) ^ ((c & 2) ? hy1 : hy0) ^ ((c & 4) ? hz1 : hz0)) & m;
            } else {
#pragma unroll
                for (int c = 0; c < 8; ++c)
                    idx[c] = ((ix + (c & 1)) ^ ((c & 2) ? hy1 : hy0) ^ ((c & 4) ? hz1 : hz0)) % hs;
            }
        } else {
            const unsigned stride = (16u << l) + 1u;
#pragma unroll
            for (int c = 0; c < 8; ++c) {
                const unsigned lin = (ix + (c & 1))
                                   + (iy + ((c >> 1) & 1)) * stride
                                   + (iz + ((c >> 2) & 1)) * stride * stride;
                idx[c] = lin % hs;
            }
        }

        float2 e[8];
#pragma unroll
        for (int c = 0; c < 8; ++c) e[c] = tab[idx[c]];

        const float wx[2] = {1.0f - fx, fx};
        const float wy[2] = {1.0f - fy, fy};
        const float wz[2] = {1.0f - fz, fz};
        float o0 = 0.0f, o1 = 0.0f;
#pragma unroll
        for (int c = 0; c < 8; ++c) {
            const float w = wx[c & 1] * wy[(c >> 1) & 1] * wz[(c >> 2) & 1];
            o0 = fmaf(w, e[c].x, o0);
            o1 = fmaf(w, e[c].y, o1);
        }
        lds[tid * 33 + l * 2 + 0] = o0;
        lds[tid * 33 + l * 2 + 1] = o1;
    }

    __syncthreads();
    float* __restrict__ ochunk = out + (long)blockIdx.x * (BLOCK * 32);
#pragma unroll
    for (int k = 0; k < 32; ++k) {
        const int flat = k * BLOCK + tid;
        const float v = lds[(flat >> 5) * 33 + (flat & 31)];
        __builtin_nontemporal_store(v, ochunk + flat);
    }
}

extern "C" void kernel_launch(void* const* d_in, const int* in_sizes, int n_in,
                              void* d_out, int out_size, void* d_ws, size_t ws_size,
                              hipStream_t stream) {
    const float* xyz = (const float*)d_in[0];
    const float* emb = (const float*)d_in[1];
    float* out = (float*)d_out;
    const int B = in_sizes[0] / 3;

    // Reproduce HashEncoder.__init__ offset arithmetic exactly.
    HashParams p;
    p.offs[0] = 0;
    unsigned hash_bits = 0, pow2_bits = 0;
    long off = 0;
    for (int i = 0; i < NLEVELS; ++i) {
        const long res = 16L << i;
        const long dense = (res + 1) * (res + 1) * (res + 1);
        long t = dense < (1L << 19) ? dense : (1L << 19);
        t = (t / 8) * 8;
        p.hsize[i] = (unsigned)t;
        off += t;
        p.offs[i + 1] = (unsigned)off;
        if (dense > t) hash_bits |= (1u << i);   // NOTE: true for ALL levels here
        if ((t & (t - 1)) == 0) pow2_bits |= (1u << i);
    }
    p.hash_bits = hash_bits;
    p.pow2_bits = pow2_bits;

    const long nent = off;                               // total table entries
    const size_t need_ws16 = (size_t)B * NLEVELS * 4;    // half2 ws
    const size_t need_h = need_ws16 + (size_t)nent * 4;  // + fp16 table (92.6 MB)
    const size_t need_f32 = (size_t)B * NLEVELS * sizeof(float2);
    const bool shape_ok = (B % (BLOCK * PPT)) == 0 && (B % BLOCK) == 0;
    // fp16 tier needs every level hashed (true for this construction whenever
    // rounding dropped entries) OR dense handled -> we only support all-hashed.
    const bool all_hashed = (hash_bits == ((1u << NLEVELS) - 1u));

    if (shape_ok && all_hashed && ws_size >= need_h) {
        // tier 1: fp16 table + half2 ws
        unsigned* tab16 = (unsigned*)((char*)d_ws + need_ws16);
        const int n2 = (int)(nent / 2);
        hashenc_conv<<<dim3((n2 + BLOCK - 1) / BLOCK), dim3(BLOCK), 0, stream>>>(
            (const float4*)emb, (uint2*)tab16, n2);
        int bpl_shift = 0;
        while ((1 << bpl_shift) * (BLOCK * PPT) < B) ++bpl_shift;  // B is pow2
        const int bpl = 1 << bpl_shift;
        hashenc_pass1_h<<<dim3(NLEVELS * bpl), dim3(BLOCK), 0, stream>>>(
            xyz, tab16, (unsigned*)d_ws, p, B, bpl_shift);
        hashenc_pass2_h<<<dim3(B / BLOCK), dim3(BLOCK), 0, stream>>>(
            (const unsigned*)d_ws, out, B);
    } else if (shape_ok && ws_size >= need_f32) {
        // tier 2: f32 two-pass
        int bpl_shift = 0;
        while ((1 << bpl_shift) * (BLOCK * PPT) < B) ++bpl_shift;
        const int bpl = 1 << bpl_shift;
        hashenc_pass1_f32<<<dim3(NLEVELS * bpl), dim3(BLOCK), 0, stream>>>(
            xyz, emb, (float2*)d_ws, p, B, bpl_shift);
        hashenc_pass2<<<dim3(B / BLOCK), dim3(BLOCK), 0, stream>>>(
            (const float2*)d_ws, out, B);
    } else {
        // tier 3: single-pass fallback
        hashenc_fwd<<<dim3(B / BLOCK), dim3(BLOCK), 0, stream>>>(xyz, emb, out, p);
    }
}

// Round 5
// 486.526 us; speedup vs baseline: 1.2005x; 1.0016x over previous
//
#include <hip/hip_runtime.h>
#include <hip/hip_fp16.h>

#define NLEVELS 16
#define BLOCK 256
#define PPT1 4   // points per thread, fp16 pass-1 (deep MLP)
#define PPT 2    // points per thread, f32 fallback pass-1

struct HashParams {
    unsigned offs[NLEVELS + 1];  // per-level table offsets (entries)
    unsigned hsize[NLEVELS];     // per-level table size (entries)
    unsigned hash_bits;          // bit l set -> hash path for level l (all, this config)
    unsigned pow2_bits;          // bit l set -> hsize[l] is a power of two
};

// ---------------- table conversion: f32x2 entry -> packed half2 (4 B) ------
// Entries are uniform(-1e-4,1e-4); fp16 step there is ~6e-8 -> rounding error
// <=3e-8/entry. Halves gather bytes AND halves each hashed level table to
// 2 MB -> L2-resident per XCD during its level phase (R4: FETCH 704->184 MB).
__global__ void __launch_bounds__(BLOCK)
hashenc_conv(const float4* __restrict__ emb2, uint2* __restrict__ tab16, int n2)
{
    const int i = blockIdx.x * BLOCK + threadIdx.x;
    if (i < n2) {
        const float4 v = emb2[i];
        const __half2 a = __floats2half2_rn(v.x, v.y);
        const __half2 b = __floats2half2_rn(v.z, v.w);
        tab16[i] = make_uint2(*(const unsigned*)&a, *(const unsigned*)&b);
    }
}

// ---------------- pass 1 (fp16 table): issue-all-then-consume, PPT=4 --------
// Level-major dispatch (blockIdx = level*bpl + chunk): each XCD's L2 holds one
// 2 MB fp16 table at a time. Phase A computes indices and issues ALL gathers
// for 4 points (16-32 loads in flight) into registers; phase B converts +
// interpolates. pass1 is L2-hit-latency bound (R4: 0.59 lane-req/cy/CU,
// VALU 20%, HBM 10%) -> deeper per-wave MLP is the remaining lever.
__global__ void __launch_bounds__(BLOCK)
hashenc_pass1_h(const float* __restrict__ xyz,
                const unsigned* __restrict__ tab16,
                unsigned* __restrict__ ws,
                HashParams p, int np, int bpl_shift)
{
    const int l = blockIdx.x >> bpl_shift;
    const int chunk = blockIdx.x & ((1 << bpl_shift) - 1);
    const int tid = threadIdx.x;

    __shared__ float sxyz[BLOCK * PPT1 * 3];  // 12 KB staged coords
    {
        const float4* __restrict__ src =
            (const float4*)(xyz + (size_t)chunk * (BLOCK * PPT1) * 3);
        float4* __restrict__ dst = (float4*)sxyz;
#pragma unroll
        for (int i = tid; i < (BLOCK * PPT1 * 3) / 4; i += BLOCK)
            dst[i] = src[i];
    }
    __syncthreads();

    const unsigned hs = p.hsize[l];
    const unsigned* __restrict__ tab = tab16 + p.offs[l];
    const float scale = (float)((16u << l) - 1u);
    const bool is_pow2 = (p.pow2_bits >> l) & 1u;
    unsigned* __restrict__ wl = ws + (size_t)l * np;

    unsigned raw[PPT1][8];    // all compile-time indexed
    unsigned selba[PPT1];     // bit q: swap r0/r1 for corner-pair q
    float fxa[PPT1], fya[PPT1], fza[PPT1];

    // ---- phase A: indices + issue all gathers ----
#pragma unroll
    for (int s = 0; s < PPT1; ++s) {
        const int lp = s * BLOCK + tid;
        const float x = sxyz[lp * 3 + 0];
        const float y = sxyz[lp * 3 + 1];
        const float z = sxyz[lp * 3 + 2];
        const float px = x * scale + 0.5f;
        const float py = y * scale + 0.5f;
        const float pz = z * scale + 0.5f;
        const float gx = floorf(px), gy = floorf(py), gz = floorf(pz);
        fxa[s] = px - gx; fya[s] = py - gy; fza[s] = pz - gz;
        const unsigned ix = (unsigned)gx, iy = (unsigned)gy, iz = (unsigned)gz;

        const unsigned hy0 = iy * 2654435761u;
        const unsigned hz0 = iz * 805459861u;
        const unsigned hy1 = hy0 + 2654435761u;
        const unsigned hz1 = hz0 + 805459861u;
        const unsigned hyz[4] = { hy0 ^ hz0, hy1 ^ hz0, hy0 ^ hz1, hy1 ^ hz1 };

        unsigned selb = 0u;
        if (is_pow2) {
            const unsigned m = hs - 1u;
            if (!(ix & 1u)) {
                // even ix: x-corners are v0 and v0^1 -> one 8 B dwordx2 pair
#pragma unroll
                for (int q = 0; q < 4; ++q) {
                    const unsigned v0 = (ix ^ hyz[q]) & m;
                    const uint2 pr = *reinterpret_cast<const uint2*>(tab + (v0 & ~1u));
                    raw[s][2 * q]     = pr.x;   // entry v0&~1
                    raw[s][2 * q + 1] = pr.y;   // entry v0|1
                    selb |= (v0 & 1u) << q;     // v0 odd -> corner cx=0 is pr.y
                }
            } else {
#pragma unroll
                for (int q = 0; q < 4; ++q) {
                    raw[s][2 * q]     = tab[(ix ^ hyz[q]) & m];
                    raw[s][2 * q + 1] = tab[((ix + 1u) ^ hyz[q]) & m];
                }
            }
        } else {
            // non-pow2 hashed levels (0-2): tables tiny & cache-hot; % is fine
#pragma unroll
            for (int q = 0; q < 4; ++q) {
                raw[s][2 * q]     = tab[(ix ^ hyz[q]) % hs];
                raw[s][2 * q + 1] = tab[((ix + 1u) ^ hyz[q]) % hs];
            }
        }
        selba[s] = selb;
    }

    // ---- phase B: convert + trilinear interp + packed store ----
#pragma unroll
    for (int s = 0; s < PPT1; ++s) {
        const float fx = fxa[s], fy = fya[s], fz = fza[s];
        const float wxv[2] = {1.0f - fx, fx};
        const float wyv[2] = {1.0f - fy, fy};
        const float wzv[2] = {1.0f - fz, fz};
        const unsigned selb = selba[s];
        float o0 = 0.0f, o1 = 0.0f;
#pragma unroll
        for (int q = 0; q < 4; ++q) {
            const unsigned r0 = raw[s][2 * q], r1 = raw[s][2 * q + 1];
            const bool sw = (selb >> q) & 1u;
            const unsigned ua = sw ? r1 : r0;   // corner cx=0
            const unsigned ub = sw ? r0 : r1;   // corner cx=1
            const float2 ea = __half22float2(*reinterpret_cast<const __half2*>(&ua));
            const float2 eb = __half22float2(*reinterpret_cast<const __half2*>(&ub));
            const float wq = wyv[q & 1] * wzv[q >> 1];
            const float w0 = wxv[0] * wq, w1 = wxv[1] * wq;
            o0 = fmaf(w0, ea.x, o0); o1 = fmaf(w0, ea.y, o1);
            o0 = fmaf(w1, eb.x, o0); o1 = fmaf(w1, eb.y, o1);
        }
        const int pidx = chunk * (BLOCK * PPT1) + s * BLOCK + tid;
        const __half2 ph = __floats2half2_rn(o0, o1);
        wl[pidx] = *(const unsigned*)&ph;   // 4 B coalesced store
    }
}

// ---------------- pass 2: LDS transpose, half2 ws -> f32 out ---------------
__global__ void __launch_bounds__(BLOCK)
hashenc_pass2_h(const unsigned* __restrict__ ws, float* __restrict__ out, int np)
{
    __shared__ float lds[BLOCK * 33];
    const int tid = threadIdx.x;
    const int p0 = blockIdx.x * BLOCK;

#pragma unroll
    for (int l = 0; l < NLEVELS; ++l) {
        const unsigned u = ws[(size_t)l * np + p0 + tid];   // coalesced 4 B/lane
        const float2 v = __half22float2(*reinterpret_cast<const __half2*>(&u));
        lds[tid * 33 + 2 * l + 0] = v.x;    // bank (tid+2l)%32: conflict-free
        lds[tid * 33 + 2 * l + 1] = v.y;
    }
    __syncthreads();
    float* __restrict__ ochunk = out + (size_t)blockIdx.x * (BLOCK * 32);
#pragma unroll
    for (int k = 0; k < 32; ++k) {
        const int flat = k * BLOCK + tid;
        const float v = lds[(flat >> 5) * 33 + (flat & 31)];
        __builtin_nontemporal_store(v, ochunk + flat);
    }
}

// ---------------- tier 2: f32 two-pass --------------------------------------
__global__ void __launch_bounds__(BLOCK)
hashenc_pass1_f32(const float* __restrict__ xyz,
                  const float* __restrict__ emb,
                  float2* __restrict__ ws,
                  HashParams p, int np, int bpl_shift)
{
    const int l = blockIdx.x >> bpl_shift;
    const int chunk = blockIdx.x & ((1 << bpl_shift) - 1);
    const int tid = threadIdx.x;

    __shared__ float sxyz[BLOCK * PPT * 3];
    {
        const float4* __restrict__ src =
            (const float4*)(xyz + (size_t)chunk * (BLOCK * PPT) * 3);
        float4* __restrict__ dst = (float4*)sxyz;
#pragma unroll
        for (int i = tid; i < (BLOCK * PPT * 3) / 4; i += BLOCK)
            dst[i] = src[i];
    }
    __syncthreads();

    const unsigned hs = p.hsize[l];
    const float2* __restrict__ tab = (const float2*)emb + p.offs[l];
    const float scale = (float)((16u << l) - 1u);
    const bool do_hash = (p.hash_bits >> l) & 1u;
    const bool is_pow2 = (p.pow2_bits >> l) & 1u;
    float2* __restrict__ wl = ws + (size_t)l * np;

#pragma unroll
    for (int s = 0; s < PPT; ++s) {
        const int lp = s * BLOCK + tid;
        const int pidx = chunk * (BLOCK * PPT) + lp;
        const float x = sxyz[lp * 3 + 0];
        const float y = sxyz[lp * 3 + 1];
        const float z = sxyz[lp * 3 + 2];
        const float px = x * scale + 0.5f;
        const float py = y * scale + 0.5f;
        const float pz = z * scale + 0.5f;
        const float gx = floorf(px), gy = floorf(py), gz = floorf(pz);
        const float fx = px - gx, fy = py - gy, fz = pz - gz;
        const unsigned ix = (unsigned)gx, iy = (unsigned)gy, iz = (unsigned)gz;
        const float wxv[2] = {1.0f - fx, fx};
        const float wyv[2] = {1.0f - fy, fy};
        const float wzv[2] = {1.0f - fz, fz};
        float o0 = 0.0f, o1 = 0.0f;
        unsigned idx[8];
        if (do_hash) {
            const unsigned hy0 = iy * 2654435761u;
            const unsigned hz0 = iz * 805459861u;
            const unsigned hy1 = hy0 + 2654435761u;
            const unsigned hz1 = hz0 + 805459861u;
            if (is_pow2) {
                const unsigned m = hs - 1u;
#pragma unroll
                for (int c = 0; c < 8; ++c)
                    idx[c] = ((ix + (c & 1)) ^ ((c & 2) ? hy1 : hy0) ^ ((c & 4) ? hz1 : hz0)) & m;
            } else {
#pragma unroll
                for (int c = 0; c < 8; ++c)
                    idx[c] = ((ix + (c & 1)) ^ ((c & 2) ? hy1 : hy0) ^ ((c & 4) ? hz1 : hz0)) % hs;
            }
        } else {
            const unsigned stride = (16u << l) + 1u;
#pragma unroll
            for (int c = 0; c < 8; ++c) {
                const unsigned lin = (ix + (c & 1))
                                   + (iy + ((c >> 1) & 1)) * stride
                                   + (iz + ((c >> 2) & 1)) * stride * stride;
                idx[c] = lin % hs;
            }
        }
        float2 e[8];
#pragma unroll
        for (int c = 0; c < 8; ++c) e[c] = tab[idx[c]];
#pragma unroll
        for (int c = 0; c < 8; ++c) {
            const float w = wxv[c & 1] * wyv[(c >> 1) & 1] * wzv[(c >> 2) & 1];
            o0 = fmaf(w, e[c].x, o0);
            o1 = fmaf(w, e[c].y, o1);
        }
        wl[pidx] = make_float2(o0, o1);
    }
}

__global__ void __launch_bounds__(BLOCK)
hashenc_pass2(const float2* __restrict__ ws, float* __restrict__ out, int np)
{
    __shared__ float lds[BLOCK * 33];
    const int tid = threadIdx.x;
    const int p0 = blockIdx.x * BLOCK;

#pragma unroll
    for (int l = 0; l < NLEVELS; ++l) {
        const float2 v = ws[(size_t)l * np + p0 + tid];
        lds[tid * 33 + 2 * l + 0] = v.x;
        lds[tid * 33 + 2 * l + 1] = v.y;
    }
    __syncthreads();
    float* __restrict__ ochunk = out + (size_t)blockIdx.x * (BLOCK * 32);
#pragma unroll
    for (int k = 0; k < 32; ++k) {
        const int flat = k * BLOCK + tid;
        const float v = lds[(flat >> 5) * 33 + (flat & 31)];
        __builtin_nontemporal_store(v, ochunk + flat);
    }
}

// ---------------- tier 3: single-pass fallback ------------------------------
__global__ void __launch_bounds__(BLOCK)
hashenc_fwd(const float* __restrict__ xyz,
            const float* __restrict__ emb,
            float* __restrict__ out,
            HashParams p)
{
    const int tid = threadIdx.x;
    const long b = (long)blockIdx.x * BLOCK + tid;
    __shared__ float lds[BLOCK * 33];

    const float x = xyz[b * 3 + 0];
    const float y = xyz[b * 3 + 1];
    const float z = xyz[b * 3 + 2];

#pragma unroll
    for (int l = 0; l < NLEVELS; ++l) {
        const float scale = (float)((16u << l) - 1u);
        const float px = x * scale + 0.5f;
        const float py = y * scale + 0.5f;
        const float pz = z * scale + 0.5f;
        const float gx = floorf(px), gy = floorf(py), gz = floorf(pz);
        const float fx = px - gx, fy = py - gy, fz = pz - gz;
        const unsigned ix = (unsigned)gx, iy = (unsigned)gy, iz = (unsigned)gz;
        const unsigned hs = p.hsize[l];
        const float2* __restrict__ tab = (const float2*)emb + p.offs[l];

        unsigned idx[8];
        if ((p.hash_bits >> l) & 1u) {
            const unsigned hy0 = iy * 2654435761u;
            const unsigned hz0 = iz * 805459861u;
            const unsigned hy1 = hy0 + 2654435761u;
            const unsigned hz1 = hz0 + 805459861u;
            if ((p.pow2_bits >> l) & 1u) {
                const unsigned m = hs - 1u;
#pragma unroll
                for (int c = 0; c < 8; ++c)
                    idx[c] = ((ix + (c & 1)) ^ ((c & 2) ? hy1 : hy0) ^ ((c & 4) ? hz1 : hz0)) & m;
            } else {
#pragma unroll
                for (int c = 0; c < 8; ++c)
                    idx[c] = ((ix + (c & 1)) ^ ((c & 2) ? hy1 : hy0) ^ ((c & 4) ? hz1 : hz0)) % hs;
            }
        } else {
            const unsigned stride = (16u << l) + 1u;
#pragma unroll
            for (int c = 0; c < 8; ++c) {
                const unsigned lin = (ix + (c & 1))
                                   + (iy + ((c >> 1) & 1)) * stride
                                   + (iz + ((c >> 2) & 1)) * stride * stride;
                idx[c] = lin % hs;
            }
        }

        float2 e[8];
#pragma unroll
        for (int c = 0; c < 8; ++c) e[c] = tab[idx[c]];

        const float wx[2] = {1.0f - fx, fx};
        const float wy[2] = {1.0f - fy, fy};
        const float wz[2] = {1.0f - fz, fz};
        float o0 = 0.0f, o1 = 0.0f;
#pragma unroll
        for (int c = 0; c < 8; ++c) {
            const float w = wx[c & 1] * wy[(c >> 1) & 1] * wz[(c >> 2) & 1];
            o0 = fmaf(w, e[c].x, o0);
            o1 = fmaf(w, e[c].y, o1);
        }
        lds[tid * 33 + l * 2 + 0] = o0;
        lds[tid * 33 + l * 2 + 1] = o1;
    }

    __syncthreads();
    float* __restrict__ ochunk = out + (long)blockIdx.x * (BLOCK * 32);
#pragma unroll
    for (int k = 0; k < 32; ++k) {
        const int flat = k * BLOCK + tid;
        const float v = lds[(flat >> 5) * 33 + (flat & 31)];
        __builtin_nontemporal_store(v, ochunk + flat);
    }
}

extern "C" void kernel_launch(void* const* d_in, const int* in_sizes, int n_in,
                              void* d_out, int out_size, void* d_ws, size_t ws_size,
                              hipStream_t stream) {
    const float* xyz = (const float*)d_in[0];
    const float* emb = (const float*)d_in[1];
    float* out = (float*)d_out;
    const int B = in_sizes[0] / 3;

    // Reproduce HashEncoder.__init__ offset arithmetic exactly.
    HashParams p;
    p.offs[0] = 0;
    unsigned hash_bits = 0, pow2_bits = 0;
    long off = 0;
    for (int i = 0; i < NLEVELS; ++i) {
        const long res = 16L << i;
        const long dense = (res + 1) * (res + 1) * (res + 1);
        long t = dense < (1L << 19) ? dense : (1L << 19);
        t = (t / 8) * 8;
        p.hsize[i] = (unsigned)t;
        off += t;
        p.offs[i + 1] = (unsigned)off;
        if (dense > t) hash_bits |= (1u << i);   // true for ALL levels here
        if ((t & (t - 1)) == 0) pow2_bits |= (1u << i);
    }
    p.hash_bits = hash_bits;
    p.pow2_bits = pow2_bits;

    const long nent = off;                               // total table entries
    const size_t need_ws16 = (size_t)B * NLEVELS * 4;    // half2 ws (64 MB)
    const size_t need_h = need_ws16 + (size_t)nent * 4;  // + fp16 table (92.6 MB)
    const size_t need_f32 = (size_t)B * NLEVELS * sizeof(float2);
    const bool shape1_ok = (B % (BLOCK * PPT1)) == 0 && (B % BLOCK) == 0;
    const bool shape2_ok = (B % (BLOCK * PPT)) == 0 && (B % BLOCK) == 0;
    const bool all_hashed = (hash_bits == ((1u << NLEVELS) - 1u));

    if (shape1_ok && all_hashed && ws_size >= need_h) {
        // tier 1: fp16 table + half2 ws, PPT=4 deep-MLP pass 1
        unsigned* tab16 = (unsigned*)((char*)d_ws + need_ws16);
        const int n2 = (int)(nent / 2);
        hashenc_conv<<<dim3((n2 + BLOCK - 1) / BLOCK), dim3(BLOCK), 0, stream>>>(
            (const float4*)emb, (uint2*)tab16, n2);
        int bpl_shift = 0;
        while ((1 << bpl_shift) * (BLOCK * PPT1) < B) ++bpl_shift;  // B is pow2
        const int bpl = 1 << bpl_shift;
        hashenc_pass1_h<<<dim3(NLEVELS * bpl), dim3(BLOCK), 0, stream>>>(
            xyz, tab16, (unsigned*)d_ws, p, B, bpl_shift);
        hashenc_pass2_h<<<dim3(B / BLOCK), dim3(BLOCK), 0, stream>>>(
            (const unsigned*)d_ws, out, B);
    } else if (shape2_ok && ws_size >= need_f32) {
        // tier 2: f32 two-pass
        int bpl_shift = 0;
        while ((1 << bpl_shift) * (BLOCK * PPT) < B) ++bpl_shift;
        const int bpl = 1 << bpl_shift;
        hashenc_pass1_f32<<<dim3(NLEVELS * bpl), dim3(BLOCK), 0, stream>>>(
            xyz, emb, (float2*)d_ws, p, B, bpl_shift);
        hashenc_pass2<<<dim3(B / BLOCK), dim3(BLOCK), 0, stream>>>(
            (const float2*)d_ws, out, B);
    } else {
        // tier 3: single-pass fallback
        hashenc_fwd<<<dim3(B / BLOCK), dim3(BLOCK), 0, stream>>>(xyz, emb, out, p);
    }
}